// Round 4
// baseline (455.770 us; speedup 1.0000x reference)
//
#include <hip/hip_runtime.h>
#include <cstdint>
#include <cstddef>

#define N_NODES 8192
#define INF 512
#define OUTF 256
#define SPLITK 8
#define MSLICE (N_NODES / SPLITK)  // 1024

typedef _Float16 f16;
typedef _Float16 f16x8 __attribute__((ext_vector_type(8)));
typedef _Float16 f16x4 __attribute__((ext_vector_type(4)));
typedef float f32x4 __attribute__((ext_vector_type(4)));

__device__ __forceinline__ void async_copy16(void* lds_dst, const void* g_src) {
  __builtin_amdgcn_global_load_lds(
      (const __attribute__((address_space(1))) void*)g_src,
      (__attribute__((address_space(3))) void*)lds_dst,
      16, 0, 0);
}

__device__ __forceinline__ float elu(float x) { return x > 0.f ? x : expm1f(x); }

// -------- prep: W [512][256] fp32 -> WhT [256][512] f16, LDS transpose -----
// 64i x 64o tiles, coalesced loads AND coalesced (vector) stores.
__global__ __launch_bounds__(256) void prep_w(const float* __restrict__ W,
                                              f16* __restrict__ WhT) {
  __shared__ float tile[64][65];  // +1 pad
  const int t = threadIdx.x;
  const int i0 = blockIdx.x * 64, o0 = blockIdx.y * 64;
  const int row = t >> 2, oc = (t & 3) * 16;
#pragma unroll
  for (int c = 0; c < 4; ++c) {
    f32x4 v = *(const f32x4*)(W + (size_t)(i0 + row) * OUTF + o0 + oc + c * 4);
    *(f32x4*)&tile[row][oc + c * 4] = v;
  }
  __syncthreads();
  const int orow = t >> 2, ic = (t & 3) * 16;
  f16x8 h0, h1;
#pragma unroll
  for (int c = 0; c < 8; ++c) h0[c] = (f16)tile[ic + c][orow];
#pragma unroll
  for (int c = 0; c < 8; ++c) h1[c] = (f16)tile[ic + 8 + c][orow];
  f16* dst = WhT + (size_t)(o0 + orow) * INF + i0 + ic;
  *(f16x8*)dst = h0;
  *(f16x8*)(dst + 8) = h1;
}

// -------- gemm1: supT[o][m] = sum_k WhT[o][k] * X[m][k]  (X cast fused) ----
__global__ __launch_bounds__(256) void gemm1(const f16* __restrict__ WhT,
                                             const float* __restrict__ X,
                                             f16* __restrict__ supT) {
  __shared__ __align__(16) f16 Asm[64 * 64];  // WhT tile, XOR chunk-swizzled
  __shared__ __align__(16) f16 Bsm[64 * 64];  // X tile (f16), XOR-swizzled
  const int t = threadIdx.x;
  const int wave = t >> 6, lane = t & 63;
  const int q = lane >> 4, r = lane & 15;
  const int lrow = lane >> 3, lchunk = lane & 7;
  const int o0 = blockIdx.x * 64, m0 = blockIdx.y * 64;

  f32x4 acc[4];
#pragma unroll
  for (int i = 0; i < 4; ++i) acc[i] = (f32x4){0.f, 0.f, 0.f, 0.f};

  const int b_row = t >> 2;
  const int b_c0 = (t & 3) * 2;
  const float* xptr = X + (size_t)(m0 + b_row) * INF + (t & 3) * 16;

  for (int kt = 0; kt < 8; ++kt) {
    const int k0 = kt * 64;
#pragma unroll
    for (int op = 0; op < 2; ++op) {
      const int row = (wave * 2 + op) * 8 + lrow;
      const f16* src = WhT + (size_t)(o0 + row) * INF + k0 + (lchunk ^ lrow) * 8;
      async_copy16(Asm + (wave * 2 + op) * 512, src);
    }
    {
      const float* xp = xptr + k0;
      f32x4 v0 = *(const f32x4*)(xp + 0);
      f32x4 v1 = *(const f32x4*)(xp + 4);
      f32x4 v2 = *(const f32x4*)(xp + 8);
      f32x4 v3 = *(const f32x4*)(xp + 12);
      f16x8 h0, h1;
#pragma unroll
      for (int u = 0; u < 4; ++u) {
        h0[u] = (f16)v0[u];
        h0[4 + u] = (f16)v1[u];
        h1[u] = (f16)v2[u];
        h1[4 + u] = (f16)v3[u];
      }
      *(f16x8*)&Bsm[b_row * 64 + ((b_c0 ^ (b_row & 7)) * 8)] = h0;
      *(f16x8*)&Bsm[b_row * 64 + (((b_c0 + 1) ^ (b_row & 7)) * 8)] = h1;
    }
    __syncthreads();
#pragma unroll
    for (int s = 0; s < 2; ++s) {
      const int pc = ((s * 4 + q) ^ (r & 7)) * 8;
      f16x8 af[4];
#pragma unroll
      for (int i = 0; i < 4; ++i) af[i] = *(const f16x8*)&Asm[(i * 16 + r) * 64 + pc];
      const f16x8 bf = *(const f16x8*)&Bsm[(wave * 16 + r) * 64 + pc];
#pragma unroll
      for (int i = 0; i < 4; ++i)
        acc[i] = __builtin_amdgcn_mfma_f32_16x16x32_f16(af[i], bf, acc[i], 0, 0, 0);
    }
    __syncthreads();
  }
  const int m = m0 + wave * 16 + r;
#pragma unroll
  for (int i = 0; i < 4; ++i)
#pragma unroll
    for (int g = 0; g < 4; ++g)
      supT[(size_t)(o0 + i * 16 + q * 4 + g) * N_NODES + m] = (f16)acc[i][g];
}

// -------- gemm2: P16[y][n][o] = sum_{m in slice y} adj[n][m]^2 * supT[o][m] --
// Block tile 128n x 256o, BK=64, split-K=8 -> grid (64,8)=512 blocks.
// 4 waves, each 128n x 64o = 8x4 16x16x32 tiles, acc = 128 regs.
// LDS = 16K (A) + 32K (B) = 48 KB. launch_bounds(256,2): no spill, 2 blocks/CU.
template <bool ATOMIC>
__global__ __launch_bounds__(256, 2) void gemm2(const float* __restrict__ adj,
                                                const f16* __restrict__ supT,
                                                f16* __restrict__ P16,
                                                float* __restrict__ outp) {
  __shared__ __align__(16) f16 Asm[128 * 64];  // adj^2 [n'][k'], XOR-swizzled
  __shared__ __align__(16) f16 Bsm[256 * 64];  // supT  [o][k'],  XOR-swizzled
  const int t = threadIdx.x;
  const int wave = t >> 6, lane = t & 63;
  const int q = lane >> 4, r = lane & 15;
  const int n0 = blockIdx.x * 128;
  const size_t m_base = (size_t)blockIdx.y * MSLICE;

  f32x4 acc[8][4];
#pragma unroll
  for (int i = 0; i < 8; ++i)
#pragma unroll
    for (int j = 0; j < 4; ++j) acc[i][j] = (f32x4){0.f, 0.f, 0.f, 0.f};

  const int a_row = t >> 1;        // n' 0..127
  const int a_half = t & 1;        // which 32-m half of the 64-m row
  const float* aptr = adj + (size_t)(n0 + a_row) * N_NODES + m_base + a_half * 32;
  const int b_o = wave * 64 + (lane >> 3);
  const int b_kb = lane & 7;

  for (int kt = 0; kt < MSLICE / 64; ++kt) {
    // B: async DMA, swizzle applied to SOURCE chunk (dst = base + lane*16)
#pragma unroll
    for (int j = 0; j < 8; ++j) {
      const int o = b_o + j * 8;
      const int kb = b_kb ^ (o & 7);
      const f16* src = supT + (size_t)o * N_NODES + m_base + kt * 64 + kb * 8;
      async_copy16(Bsm + (wave * 64 + j * 8) * 64, src);
    }
    // A: 32 fp32 per thread, square, cvt, 4x ds_write_b128 XOR-swizzled
    {
      const float* ap = aptr + kt * 64;
      f32x4 v[8];
#pragma unroll
      for (int c = 0; c < 8; ++c) v[c] = *(const f32x4*)(ap + c * 4);
#pragma unroll
      for (int c = 0; c < 4; ++c) {
        f16x8 h;
#pragma unroll
        for (int u = 0; u < 4; ++u) {
          h[u] = (f16)(v[2 * c][u] * v[2 * c][u]);
          h[4 + u] = (f16)(v[2 * c + 1][u] * v[2 * c + 1][u]);
        }
        const int lc = a_half * 4 + c;  // logical chunk 0..7
        *(f16x8*)&Asm[a_row * 64 + ((lc ^ (a_row & 7)) * 8)] = h;
      }
    }
    __syncthreads();
#pragma unroll
    for (int s = 0; s < 2; ++s) {
      const int pc = ((s * 4 + q) ^ (r & 7)) * 8;
      f16x8 af[8], bf[4];
#pragma unroll
      for (int i = 0; i < 8; ++i)
        af[i] = *(const f16x8*)&Asm[(i * 16 + r) * 64 + pc];
#pragma unroll
      for (int j = 0; j < 4; ++j)
        bf[j] = *(const f16x8*)&Bsm[(wave * 64 + j * 16 + r) * 64 + pc];
#pragma unroll
      for (int i = 0; i < 8; ++i)
#pragma unroll
        for (int j = 0; j < 4; ++j)
          acc[i][j] = __builtin_amdgcn_mfma_f32_16x16x32_f16(af[i], bf[j],
                                                             acc[i][j], 0, 0, 0);
    }
    __syncthreads();
  }
  if (ATOMIC) {
#pragma unroll
    for (int i = 0; i < 8; ++i)
#pragma unroll
      for (int g = 0; g < 4; ++g) {
        const int n = n0 + i * 16 + q * 4 + g;
        float* orow = outp + (size_t)n * OUTF + wave * 64 + r;
#pragma unroll
        for (int j = 0; j < 4; ++j) atomicAdd(orow + j * 16, acc[i][j][g]);
      }
  } else {
    f16* base = P16 + (size_t)blockIdx.y * N_NODES * OUTF;
#pragma unroll
    for (int i = 0; i < 8; ++i)
#pragma unroll
      for (int g = 0; g < 4; ++g) {
        const int n = n0 + i * 16 + q * 4 + g;
        f16* orow = base + (size_t)n * OUTF + wave * 64 + r;
#pragma unroll
        for (int j = 0; j < 4; ++j) orow[j * 16] = (f16)acc[i][j][g];
      }
  }
}

// -------- epilogue A: sum 8 f16 partial planes + bias + ELU --------
__global__ __launch_bounds__(256) void reduce_elu(const f16* __restrict__ P16,
                                                  const float* __restrict__ bias,
                                                  float* __restrict__ out) {
  const int idx = blockIdx.x * 256 + threadIdx.x;  // float4 index
  f32x4 s = (f32x4){0.f, 0.f, 0.f, 0.f};
#pragma unroll
  for (int y = 0; y < SPLITK; ++y) {
    const f16x4 h = ((const f16x4*)(P16 + (size_t)y * N_NODES * OUTF))[idx];
#pragma unroll
    for (int u = 0; u < 4; ++u) s[u] += (float)h[u];
  }
  const f32x4 b = ((const f32x4*)bias)[idx & 63];
  f32x4 v;
#pragma unroll
  for (int u = 0; u < 4; ++u) v[u] = elu(s[u] + b[u]);
  ((f32x4*)out)[idx] = v;
}

// -------- epilogue B (atomic fallback): in-place bias + ELU --------
__global__ __launch_bounds__(256) void bias_elu(float* __restrict__ out,
                                                const float* __restrict__ bias) {
  const int idx = blockIdx.x * 256 + threadIdx.x;
  f32x4 v = ((const f32x4*)out)[idx];
  const f32x4 b = ((const f32x4*)bias)[idx & 63];
#pragma unroll
  for (int u = 0; u < 4; ++u) v[u] = elu(v[u] + b[u]);
  ((f32x4*)out)[idx] = v;
}

extern "C" void kernel_launch(void* const* d_in, const int* in_sizes, int n_in,
                              void* d_out, int out_size, void* d_ws, size_t ws_size,
                              hipStream_t stream) {
  const float* X = (const float*)d_in[0];     // [8192, 512]
  const float* adj = (const float*)d_in[1];   // [8192, 8192]
  const float* W = (const float*)d_in[2];     // [512, 256]
  const float* bias = (const float*)d_in[3];  // [256]
  float* out = (float*)d_out;                 // [8192, 256] fp32

  char* ws = (char*)d_ws;
  f16* supT = (f16*)(ws + 0);           // 4 MB
  f16* WhT = (f16*)(ws + (4u << 20));   // 256 KB
  f16* P16 = (f16*)(ws + (8u << 20));   // 32 MB f16 partials
  const size_t need = (40u << 20);

  prep_w<<<dim3(INF / 64, OUTF / 64), 256, 0, stream>>>(W, WhT);
  gemm1<<<dim3(OUTF / 64, N_NODES / 64), 256, 0, stream>>>(WhT, X, supT);
  if (ws_size >= need) {
    gemm2<false><<<dim3(N_NODES / 128, SPLITK), 256, 0, stream>>>(adj, supT, P16, nullptr);
    reduce_elu<<<N_NODES * OUTF / 4 / 256, 256, 0, stream>>>(P16, bias, out);
  } else {
    hipMemsetAsync(d_out, 0, (size_t)out_size * sizeof(float), stream);
    gemm2<true><<<dim3(N_NODES / 128, SPLITK), 256, 0, stream>>>(adj, supT, nullptr, out);
    bias_elu<<<N_NODES * OUTF / 4 / 256, 256, 0, stream>>>(out, bias);
  }
}

// Round 5
// 434.652 us; speedup vs baseline: 1.0486x; 1.0486x over previous
//
#include <hip/hip_runtime.h>
#include <cstdint>
#include <cstddef>

#define N_NODES 8192
#define INF 512
#define OUTF 256
#define SPLITK 8
#define MSLICE (N_NODES / SPLITK)  // 1024

typedef _Float16 f16;
typedef _Float16 f16x8 __attribute__((ext_vector_type(8)));
typedef _Float16 f16x4 __attribute__((ext_vector_type(4)));
typedef float f32x4 __attribute__((ext_vector_type(4)));

__device__ __forceinline__ void async_copy16(void* lds_dst, const void* g_src) {
  __builtin_amdgcn_global_load_lds(
      (const __attribute__((address_space(1))) void*)g_src,
      (__attribute__((address_space(3))) void*)lds_dst,
      16, 0, 0);
}

__device__ __forceinline__ float elu(float x) { return x > 0.f ? x : expm1f(x); }

// -------- prep: W [512][256] fp32 -> WhT [256][512] f16, LDS transpose -----
__global__ __launch_bounds__(256) void prep_w(const float* __restrict__ W,
                                              f16* __restrict__ WhT) {
  __shared__ float tile[64][65];  // +1 pad
  const int t = threadIdx.x;
  const int i0 = blockIdx.x * 64, o0 = blockIdx.y * 64;
  const int row = t >> 2, oc = (t & 3) * 16;
#pragma unroll
  for (int c = 0; c < 4; ++c) {
    f32x4 v = *(const f32x4*)(W + (size_t)(i0 + row) * OUTF + o0 + oc + c * 4);
    *(f32x4*)&tile[row][oc + c * 4] = v;
  }
  __syncthreads();
  const int orow = t >> 2, ic = (t & 3) * 16;
  f16x8 h0, h1;
#pragma unroll
  for (int c = 0; c < 8; ++c) h0[c] = (f16)tile[ic + c][orow];
#pragma unroll
  for (int c = 0; c < 8; ++c) h1[c] = (f16)tile[ic + 8 + c][orow];
  f16* dst = WhT + (size_t)(o0 + orow) * INF + i0 + ic;
  *(f16x8*)dst = h0;
  *(f16x8*)(dst + 8) = h1;
}

// -------- gemm1: supT[o][m] = sum_k WhT[o][k] * X[m][k]  (X cast fused) ----
__global__ __launch_bounds__(256) void gemm1(const f16* __restrict__ WhT,
                                             const float* __restrict__ X,
                                             f16* __restrict__ supT) {
  __shared__ __align__(16) f16 Asm[64 * 64];  // WhT tile, XOR chunk-swizzled
  __shared__ __align__(16) f16 Bsm[64 * 64];  // X tile (f16), XOR-swizzled
  const int t = threadIdx.x;
  const int wave = t >> 6, lane = t & 63;
  const int q = lane >> 4, r = lane & 15;
  const int lrow = lane >> 3, lchunk = lane & 7;
  const int o0 = blockIdx.x * 64, m0 = blockIdx.y * 64;

  f32x4 acc[4];
#pragma unroll
  for (int i = 0; i < 4; ++i) acc[i] = (f32x4){0.f, 0.f, 0.f, 0.f};

  const int b_row = t >> 2;
  const int b_c0 = (t & 3) * 2;
  const float* xptr = X + (size_t)(m0 + b_row) * INF + (t & 3) * 16;

  for (int kt = 0; kt < 8; ++kt) {
    const int k0 = kt * 64;
#pragma unroll
    for (int op = 0; op < 2; ++op) {
      const int row = (wave * 2 + op) * 8 + lrow;
      const f16* src = WhT + (size_t)(o0 + row) * INF + k0 + (lchunk ^ lrow) * 8;
      async_copy16(Asm + (wave * 2 + op) * 512, src);
    }
    {
      const float* xp = xptr + k0;
      f32x4 v0 = *(const f32x4*)(xp + 0);
      f32x4 v1 = *(const f32x4*)(xp + 4);
      f32x4 v2 = *(const f32x4*)(xp + 8);
      f32x4 v3 = *(const f32x4*)(xp + 12);
      f16x8 h0, h1;
#pragma unroll
      for (int u = 0; u < 4; ++u) {
        h0[u] = (f16)v0[u];
        h0[4 + u] = (f16)v1[u];
        h1[u] = (f16)v2[u];
        h1[4 + u] = (f16)v3[u];
      }
      *(f16x8*)&Bsm[b_row * 64 + ((b_c0 ^ (b_row & 7)) * 8)] = h0;
      *(f16x8*)&Bsm[b_row * 64 + (((b_c0 + 1) ^ (b_row & 7)) * 8)] = h1;
    }
    __syncthreads();
#pragma unroll
    for (int s = 0; s < 2; ++s) {
      const int pc = ((s * 4 + q) ^ (r & 7)) * 8;
      f16x8 af[4];
#pragma unroll
      for (int i = 0; i < 4; ++i) af[i] = *(const f16x8*)&Asm[(i * 16 + r) * 64 + pc];
      const f16x8 bf = *(const f16x8*)&Bsm[(wave * 16 + r) * 64 + pc];
#pragma unroll
      for (int i = 0; i < 4; ++i)
        acc[i] = __builtin_amdgcn_mfma_f32_16x16x32_f16(af[i], bf, acc[i], 0, 0, 0);
    }
    __syncthreads();
  }
  const int m = m0 + wave * 16 + r;
#pragma unroll
  for (int i = 0; i < 4; ++i)
#pragma unroll
    for (int g = 0; g < 4; ++g)
      supT[(size_t)(o0 + i * 16 + q * 4 + g) * N_NODES + m] = (f16)acc[i][g];
}

// -------- gemm2: P16[y][n][o] = sum_{m in slice y} adj[n][m]^2 * supT[o][m] --
// R3 tile: 64n x 256o, BK=64, split-K=8 -> grid (128,8)=1024 blocks.
// acc 4x4 (64 AGPR) + ~80 arch VGPR = ~144/wave. launch_bounds(256,3):
// reg cap 170 (no spill, unlike (256,4)'s 128-cap which spilled), 3 blocks/CU.
// LDS = 8K (A) + 32K (B) = 40960 B -> 3 blocks also fit by LDS (120K/160K).
template <bool ATOMIC>
__global__ __launch_bounds__(256, 3) void gemm2(const float* __restrict__ adj,
                                                const f16* __restrict__ supT,
                                                f16* __restrict__ P16,
                                                float* __restrict__ outp) {
  __shared__ __align__(16) f16 Asm[64 * 64];   // adj^2 [n'][k'], XOR-swizzled
  __shared__ __align__(16) f16 Bsm[256 * 64];  // supT  [o][k'],  XOR-swizzled
  const int t = threadIdx.x;
  const int wave = t >> 6, lane = t & 63;
  const int q = lane >> 4, r = lane & 15;
  const int n0 = blockIdx.x * 64;
  const size_t m_base = (size_t)blockIdx.y * MSLICE;

  f32x4 acc[4][4];
#pragma unroll
  for (int i = 0; i < 4; ++i)
#pragma unroll
    for (int j = 0; j < 4; ++j) acc[i][j] = (f32x4){0.f, 0.f, 0.f, 0.f};

  const int a_row = t >> 2;
  const int a_c0 = (t & 3) * 2;
  const float* aptr = adj + (size_t)(n0 + a_row) * N_NODES + m_base + (t & 3) * 16;
  const int b_o = wave * 64 + (lane >> 3);
  const int b_kb = lane & 7;

  for (int kt = 0; kt < MSLICE / 64; ++kt) {
    // B: async DMA, swizzle applied to SOURCE chunk (dst = base + lane*16)
#pragma unroll
    for (int j = 0; j < 8; ++j) {
      const int o = b_o + j * 8;
      const int kb = b_kb ^ (o & 7);
      const f16* src = supT + (size_t)o * N_NODES + m_base + kt * 64 + kb * 8;
      async_copy16(Bsm + (wave * 64 + j * 8) * 64, src);
    }
    // A: 16 fp32, square, cvt, 2x ds_write_b128 XOR-swizzled
    {
      const float* ap = aptr + kt * 64;
      f32x4 v0 = *(const f32x4*)(ap + 0);
      f32x4 v1 = *(const f32x4*)(ap + 4);
      f32x4 v2 = *(const f32x4*)(ap + 8);
      f32x4 v3 = *(const f32x4*)(ap + 12);
      f16x8 h0, h1;
#pragma unroll
      for (int u = 0; u < 4; ++u) {
        h0[u] = (f16)(v0[u] * v0[u]);
        h0[4 + u] = (f16)(v1[u] * v1[u]);
        h1[u] = (f16)(v2[u] * v2[u]);
        h1[4 + u] = (f16)(v3[u] * v3[u]);
      }
      *(f16x8*)&Asm[a_row * 64 + ((a_c0 ^ (a_row & 7)) * 8)] = h0;
      *(f16x8*)&Asm[a_row * 64 + (((a_c0 + 1) ^ (a_row & 7)) * 8)] = h1;
    }
    __syncthreads();
#pragma unroll
    for (int s = 0; s < 2; ++s) {
      const int pc = ((s * 4 + q) ^ (r & 7)) * 8;
      f16x8 af[4], bf[4];
#pragma unroll
      for (int i = 0; i < 4; ++i) af[i] = *(const f16x8*)&Asm[(i * 16 + r) * 64 + pc];
#pragma unroll
      for (int j = 0; j < 4; ++j)
        bf[j] = *(const f16x8*)&Bsm[(wave * 64 + j * 16 + r) * 64 + pc];
#pragma unroll
      for (int i = 0; i < 4; ++i)
#pragma unroll
        for (int j = 0; j < 4; ++j)
          acc[i][j] = __builtin_amdgcn_mfma_f32_16x16x32_f16(af[i], bf[j],
                                                             acc[i][j], 0, 0, 0);
    }
    __syncthreads();
  }
  if (ATOMIC) {
#pragma unroll
    for (int i = 0; i < 4; ++i)
#pragma unroll
      for (int g = 0; g < 4; ++g) {
        const int n = n0 + i * 16 + q * 4 + g;
        float* orow = outp + (size_t)n * OUTF + wave * 64 + r;
#pragma unroll
        for (int j = 0; j < 4; ++j) atomicAdd(orow + j * 16, acc[i][j][g]);
      }
  } else {
    f16* base = P16 + (size_t)blockIdx.y * N_NODES * OUTF;
#pragma unroll
    for (int i = 0; i < 4; ++i)
#pragma unroll
      for (int g = 0; g < 4; ++g) {
        const int n = n0 + i * 16 + q * 4 + g;
        f16* orow = base + (size_t)n * OUTF + wave * 64 + r;
#pragma unroll
        for (int j = 0; j < 4; ++j) orow[j * 16] = (f16)acc[i][j][g];
      }
  }
}

// -------- epilogue A: sum 8 f16 partial planes + bias + ELU --------
__global__ __launch_bounds__(256) void reduce_elu(const f16* __restrict__ P16,
                                                  const float* __restrict__ bias,
                                                  float* __restrict__ out) {
  const int idx = blockIdx.x * 256 + threadIdx.x;  // float4 index
  f32x4 s = (f32x4){0.f, 0.f, 0.f, 0.f};
#pragma unroll
  for (int y = 0; y < SPLITK; ++y) {
    const f16x4 h = ((const f16x4*)(P16 + (size_t)y * N_NODES * OUTF))[idx];
#pragma unroll
    for (int u = 0; u < 4; ++u) s[u] += (float)h[u];
  }
  const f32x4 b = ((const f32x4*)bias)[idx & 63];
  f32x4 v;
#pragma unroll
  for (int u = 0; u < 4; ++u) v[u] = elu(s[u] + b[u]);
  ((f32x4*)out)[idx] = v;
}

// -------- epilogue B (atomic fallback): in-place bias + ELU --------
__global__ __launch_bounds__(256) void bias_elu(float* __restrict__ out,
                                                const float* __restrict__ bias) {
  const int idx = blockIdx.x * 256 + threadIdx.x;
  f32x4 v = ((const f32x4*)out)[idx];
  const f32x4 b = ((const f32x4*)bias)[idx & 63];
#pragma unroll
  for (int u = 0; u < 4; ++u) v[u] = elu(v[u] + b[u]);
  ((f32x4*)out)[idx] = v;
}

extern "C" void kernel_launch(void* const* d_in, const int* in_sizes, int n_in,
                              void* d_out, int out_size, void* d_ws, size_t ws_size,
                              hipStream_t stream) {
  const float* X = (const float*)d_in[0];     // [8192, 512]
  const float* adj = (const float*)d_in[1];   // [8192, 8192]
  const float* W = (const float*)d_in[2];     // [512, 256]
  const float* bias = (const float*)d_in[3];  // [256]
  float* out = (float*)d_out;                 // [8192, 256] fp32

  char* ws = (char*)d_ws;
  f16* supT = (f16*)(ws + 0);           // 4 MB
  f16* WhT = (f16*)(ws + (4u << 20));   // 256 KB
  f16* P16 = (f16*)(ws + (8u << 20));   // 32 MB f16 partials
  const size_t need = (40u << 20);

  prep_w<<<dim3(INF / 64, OUTF / 64), 256, 0, stream>>>(W, WhT);
  gemm1<<<dim3(OUTF / 64, N_NODES / 64), 256, 0, stream>>>(WhT, X, supT);
  if (ws_size >= need) {
    gemm2<false><<<dim3(N_NODES / 64, SPLITK), 256, 0, stream>>>(adj, supT, P16, nullptr);
    reduce_elu<<<N_NODES * OUTF / 4 / 256, 256, 0, stream>>>(P16, bias, out);
  } else {
    hipMemsetAsync(d_out, 0, (size_t)out_size * sizeof(float), stream);
    gemm2<true><<<dim3(N_NODES / 64, SPLITK), 256, 0, stream>>>(adj, supT, nullptr, out);
    bias_elu<<<N_NODES * OUTF / 4 / 256, 256, 0, stream>>>(out, bias);
  }
}